// Round 7
// baseline (1495.213 us; speedup 1.0000x reference)
//
#include <hip/hip_runtime.h>
#include <hip/hip_bf16.h>

#define CC 64
#define HIDN 128
#define DCC 16
#define HH 128
#define WW 128
#define HWS (HH*WW)        // 16384
#define BB 16
#define NPIX (BB*HWS)      // 262144

typedef __hip_bfloat16 bf16;
typedef __attribute__((ext_vector_type(8))) unsigned short ushort8;
typedef __attribute__((ext_vector_type(4))) unsigned short ushort4v;
typedef __attribute__((ext_vector_type(4))) float float4v;
typedef __attribute__((ext_vector_type(8))) short bf16x8;
typedef __attribute__((ext_vector_type(4))) float f32x4;

__device__ __forceinline__ float rcp_fast(float x){ return __builtin_amdgcn_rcpf(x); }
__device__ __forceinline__ float ftanh(float x){
    float e = __expf(2.f*x);
    return 1.f - 2.f*rcp_fast(e + 1.f);
}
__device__ __forceinline__ float fsig(float x){
    return rcp_fast(1.f + __expf(-x));
}
__device__ __forceinline__ float fgelu(float x){
    return x * fsig(x*(1.5957691216f + 0.07135481283f*x*x));
}
__device__ __forceinline__ float b2f(bf16 v){ return __bfloat162float(v); }
__device__ __forceinline__ bf16  f2b(float v){ return __float2bfloat16(v); }
__device__ __forceinline__ float u2f(unsigned short u){
    unsigned v = ((unsigned)u) << 16; return __uint_as_float(v);
}
__device__ __forceinline__ unsigned short f2u(float f){
    bf16 h = __float2bfloat16(f);
    return *reinterpret_cast<unsigned short*>(&h);
}
__device__ __forceinline__ bf16x8 packf(float4v a, float4v b){
    bf16x8 r;
    r[0]=(short)f2u(a.x); r[1]=(short)f2u(a.y); r[2]=(short)f2u(a.z); r[3]=(short)f2u(a.w);
    r[4]=(short)f2u(b.x); r[5]=(short)f2u(b.y); r[6]=(short)f2u(b.z); r[7]=(short)f2u(b.w);
    return r;
}

// ---------------------------------------------------------------- convert
__global__ __launch_bounds__(256) void k_convert(const float* __restrict__ in,
                                                 bf16* __restrict__ out, int n){
    int i = (blockIdx.x*256 + threadIdx.x) * 8;
    if (i >= n) return;
    const float4v* ip = reinterpret_cast<const float4v*>(in + i);
    float4v a = ip[0], b = ip[1];
    ushort8 o;
    o[0]=f2u(a.x); o[1]=f2u(a.y); o[2]=f2u(a.z); o[3]=f2u(a.w);
    o[4]=f2u(b.x); o[5]=f2u(b.y); o[6]=f2u(b.z); o[7]=f2u(b.w);
    *reinterpret_cast<ushort8*>(out + i) = o;
}

// ---------------------------------------------------------------- gate (MFMA, zero-shuffle chain)
__global__ __launch_bounds__(256,2) void k_gate(
    const bf16* __restrict__ xin,
    const float* __restrict__ wz1, const float* __restrict__ bz1,
    const float* __restrict__ wz2, const float* __restrict__ bz2,
    const float* __restrict__ wf1, const float* __restrict__ bf1,
    const float* __restrict__ wf2, const float* __restrict__ bf2,
    bf16* __restrict__ vout)
{
    const int t = threadIdx.x;
    const int lane = t & 63;
    const int wv = t >> 6;
    const int col = lane & 15;
    const int g = lane >> 4;
    const int blk = blockIdx.x;
    const int b = blk >> 5;
    const int sp0 = (blk & 31) << 9;

    bf16x8 Az1[4][2], Af1[4][2], Az2[4][2], Af2[4][2];
    #pragma unroll
    for (int ot=0; ot<4; ++ot){
        #pragma unroll
        for (int kh=0; kh<2; ++kh){
            const float* p;
            p = wz1 + (ot*16+col)*64 + kh*32 + g*8;
            Az1[ot][kh] = packf(*(const float4v*)p, *(const float4v*)(p+4));
            p = wf1 + (ot*16+col)*64 + kh*32 + g*8;
            Af1[ot][kh] = packf(*(const float4v*)p, *(const float4v*)(p+4));
            p = wz2 + (ot*16+col)*64 + kh*32 + g*4;
            Az2[ot][kh] = packf(*(const float4v*)p, *(const float4v*)(p+16));
            p = wf2 + (ot*16+col)*64 + kh*32 + g*4;
            Af2[ot][kh] = packf(*(const float4v*)p, *(const float4v*)(p+16));
        }
    }
    const bf16* xb = xin + (size_t)b*CC*HWS;
    bf16*       vb = vout + (size_t)b*CC*HWS;

    for (int it = wv; it < 32; it += 4){
        const int px = sp0 + it*16 + col;
        bf16x8 Bx[2];
        #pragma unroll
        for (int kh=0; kh<2; ++kh)
            #pragma unroll
            for (int j=0; j<8; ++j){
                int c = kh*32 + g*8 + j;
                Bx[kh][j] = *reinterpret_cast<const short*>(xb + (size_t)c*HWS + px);
            }
        f32x4 Dz[4], Df[4];
        #pragma unroll
        for (int ot=0; ot<4; ++ot){
            Dz[ot] = *(const f32x4*)(bz1 + ot*16 + g*4);
            Df[ot] = *(const f32x4*)(bf1 + ot*16 + g*4);
        }
        #pragma unroll
        for (int kh=0; kh<2; ++kh)
            #pragma unroll
            for (int ot=0; ot<4; ++ot){
                Dz[ot] = __builtin_amdgcn_mfma_f32_16x16x32_bf16(Az1[ot][kh], Bx[kh], Dz[ot], 0,0,0);
                Df[ot] = __builtin_amdgcn_mfma_f32_16x16x32_bf16(Af1[ot][kh], Bx[kh], Df[ot], 0,0,0);
            }
        #pragma unroll
        for (int ot=0; ot<4; ++ot)
            #pragma unroll
            for (int r=0; r<4; ++r){
                Dz[ot][r] = ftanh(Dz[ot][r]);
                Df[ot][r] = ftanh(Df[ot][r]);
            }
        bf16x8 Bz[2], Bf[2];
        #pragma unroll
        for (int kh=0; kh<2; ++kh)
            #pragma unroll
            for (int j=0; j<4; ++j){
                Bz[kh][j]   = (short)f2u(Dz[2*kh][j]);
                Bz[kh][4+j] = (short)f2u(Dz[2*kh+1][j]);
                Bf[kh][j]   = (short)f2u(Df[2*kh][j]);
                Bf[kh][4+j] = (short)f2u(Df[2*kh+1][j]);
            }
        f32x4 Ez[4], Ef[4];
        #pragma unroll
        for (int ot=0; ot<4; ++ot){
            Ez[ot] = *(const f32x4*)(bz2 + ot*16 + g*4);
            Ef[ot] = *(const f32x4*)(bf2 + ot*16 + g*4);
        }
        #pragma unroll
        for (int kh=0; kh<2; ++kh)
            #pragma unroll
            for (int ot=0; ot<4; ++ot){
                Ez[ot] = __builtin_amdgcn_mfma_f32_16x16x32_bf16(Az2[ot][kh], Bz[kh], Ez[ot], 0,0,0);
                Ef[ot] = __builtin_amdgcn_mfma_f32_16x16x32_bf16(Af2[ot][kh], Bf[kh], Ef[ot], 0,0,0);
            }
        #pragma unroll
        for (int ot=0; ot<4; ++ot)
            #pragma unroll
            for (int r=0; r<4; ++r){
                float Zv = ftanh(Ez[ot][r]);
                float Fv = fsig(Ef[ot][r]);
                *reinterpret_cast<unsigned short*>(vb + (size_t)(ot*16+g*4+r)*HWS + px)
                    = f2u((1.f - Fv)*Zv);
            }
    }
}

// ---------------------------------------------------------------- pconv (16->16, 3x3), 4 px/thread
__global__ __launch_bounds__(256) void k_pconv(
    const bf16* __restrict__ v, const float* __restrict__ w, bf16* __restrict__ x1)
{
    int gid = blockIdx.x*256 + threadIdx.x;
    int b = gid >> 12;
    int sp4 = (gid & 4095) << 2;
    int y = sp4 >> 7, x0 = sp4 & 127;
    const bf16* vb = v + (size_t)b*CC*HWS;
    float acc[DCC][4];
    #pragma unroll
    for (int o=0;o<DCC;++o)
        #pragma unroll
        for (int i=0;i<4;++i) acc[o][i] = 0.f;

    #pragma unroll 1
    for (int ic=0; ic<DCC; ++ic){
        const bf16* ip = vb + (size_t)ic*HWS;
        float xv[3][6];
        #pragma unroll
        for (int ky=0;ky<3;++ky){
            int yy = y + ky - 1;
            if (yy >= 0 && yy < HH){
                const bf16* rp = ip + yy*WW + x0;
                ushort4v mv = *reinterpret_cast<const ushort4v*>(rp);
                xv[ky][1]=u2f(mv[0]); xv[ky][2]=u2f(mv[1]);
                xv[ky][3]=u2f(mv[2]); xv[ky][4]=u2f(mv[3]);
                xv[ky][0] = (x0>0)     ? b2f(rp[-1]) : 0.f;
                xv[ky][5] = (x0+4<WW)  ? b2f(rp[4])  : 0.f;
            } else {
                #pragma unroll
                for (int i=0;i<6;++i) xv[ky][i] = 0.f;
            }
        }
        #pragma unroll
        for (int o=0;o<DCC;++o){
            const float* wp = w + (size_t)(o*DCC+ic)*9;
            #pragma unroll
            for (int ky=0;ky<3;++ky){
                float w0 = wp[ky*3+0], w1 = wp[ky*3+1], w2 = wp[ky*3+2];
                #pragma unroll
                for (int i=0;i<4;++i)
                    acc[o][i] = fmaf(w0, xv[ky][i],
                                fmaf(w1, xv[ky][i+1],
                                fmaf(w2, xv[ky][i+2], acc[o][i])));
            }
        }
    }
    bf16* xo = x1 + (size_t)b*DCC*HWS + sp4;
    #pragma unroll
    for (int o=0;o<DCC;++o){
        ushort4v ov;
        #pragma unroll
        for (int i=0;i<4;++i) ov[i] = f2u(acc[o][i]);
        *reinterpret_cast<ushort4v*>(xo + (size_t)o*HWS) = ov;
    }
}

// ---------------------------------------------------------------- fused mid: lin1+gelu+dwconv+gelu+gate+lin2+residual
// Block: 512 thr (8 waves), 4 output rows x 128 px. Wave w: row r=w&3, out-ch half og=w>>2.
// amdgpu_waves_per_eu(1,2): the 148 KB LDS already caps us at 1 block/CU (2 waves/EU),
// so tell the allocator the VGPR budget is 256 — R4-R6 showed it pins 128 and spills
// (WRITE_SIZE 170-515 MB vs ~35 MB true output). A1g/A2 fragments are built
// phase-locally (only used in the lin2 phase) to shorten live ranges.
__global__ __launch_bounds__(512)
__attribute__((amdgpu_waves_per_eu(1,2)))
void k_mid(
    const bf16* __restrict__ x1, const bf16* __restrict__ v,
    const float* __restrict__ l1w, const float* __restrict__ l1b,
    const float* __restrict__ dww, const float* __restrict__ dwb,
    const float* __restrict__ w2,  const float* __restrict__ l2b,
    bf16* __restrict__ xout,
    const float* __restrict__ xinit,   // non-null on last layer
    bf16* __restrict__ xsum)           // separate buffer (NOT v: halo race)
{
    __shared__ __align__(16) unsigned short xs[768*64];    // [px][ch] swizzled, 98304 B
    __shared__ __align__(16) unsigned short h1b[32*776];   // [cj][776], 49664 B
    const int t = threadIdx.x;
    const int lane = t & 63;
    const int w = t >> 6;
    const int col = lane & 15;
    const int g = lane >> 4;
    const int r = w & 3;
    const int og = w >> 2;
    const int blk = blockIdx.x;
    const int b = blk >> 5;
    const int y0 = (blk & 31) << 2;

    // ---- stage x-cat: 64 ch x 6 rows(y0-1..y0+4) x 128 px, transposed+swizzled
    {
        const int ch = t & 63;
        const int wg = t >> 6;
        const bf16* src = (ch < DCC) ? x1 + ((size_t)b*DCC + ch)*HWS
                                     : v  + ((size_t)b*CC  + ch)*HWS;
        #pragma unroll
        for (int i=0;i<12;++i){
            int pxg = wg*12 + i;          // 0..95
            int bufpx = pxg << 3;
            int rr = bufpx >> 7;
            int xcol = bufpx & 127;
            int gy = y0 - 1 + rr;
            ushort8 val;
            #pragma unroll
            for (int j=0;j<8;++j) val[j] = 0;
            if (gy >= 0 && gy < HH)
                val = *reinterpret_cast<const ushort8*>(src + (size_t)gy*WW + xcol);
            #pragma unroll
            for (int j=0;j<8;++j){
                int px = bufpx + j;
                *(unsigned short*)((char*)xs + px*128 + ((ch*2) ^ ((px&7)<<4))) = val[j];
            }
        }
    }
    __syncthreads();

    f32x4 Dx[8][2];
    #pragma unroll
    for (int pt=0;pt<8;++pt)
        #pragma unroll
        for (int ot=0;ot<2;++ot)
            Dx[pt][ot] = *(const f32x4*)(l2b + og*32 + ot*16 + g*4);

    const int cjdw = t & 31;          // dw: channel within chunk
    const int pxg  = (t>>5) & 15;     // dw: 8-px group

    #pragma unroll 1
    for (int cc=0; cc<4; ++cc){
        // ---- pass A fragments (h1 weights only — A1g/A2 built later, phase-local)
        bf16x8 A1h[2][2];
        #pragma unroll
        for (int t2=0;t2<2;++t2)
          #pragma unroll
          for (int kh=0;kh<2;++kh){
            bf16x8 fa;
            #pragma unroll
            for (int j=0;j<8;++j){
                int cin = kh*32 + g*8 + j;
                fa[j] = (short)f2u(l1w[cin*256 + cc*32 + t2*16 + col]);
            }
            A1h[t2][kh]=fa;
          }
        // ---- pass A: h1 chunk (32 ch) on 6 rows -> h1buf
        #pragma unroll
        for (int q=0;q<6;++q){
            int idx = w*6 + q;
            int rr = idx >> 3, pt = idx & 7;
            int px = rr*128 + pt*16 + col;
            bf16x8 B0 = *(const bf16x8*)((char*)xs + px*128 + ((g*16) ^ ((px&7)<<4)));
            bf16x8 B1 = *(const bf16x8*)((char*)xs + px*128 + ((64 + g*16) ^ ((px&7)<<4)));
            f32x4 D0 = *(const f32x4*)(l1b + cc*32 + g*4);
            f32x4 D1 = *(const f32x4*)(l1b + cc*32 + 16 + g*4);
            D0 = __builtin_amdgcn_mfma_f32_16x16x32_bf16(A1h[0][0], B0, D0, 0,0,0);
            D0 = __builtin_amdgcn_mfma_f32_16x16x32_bf16(A1h[0][1], B1, D0, 0,0,0);
            D1 = __builtin_amdgcn_mfma_f32_16x16x32_bf16(A1h[1][0], B0, D1, 0,0,0);
            D1 = __builtin_amdgcn_mfma_f32_16x16x32_bf16(A1h[1][1], B1, D1, 0,0,0);
            #pragma unroll
            for (int rr2=0;rr2<4;++rr2){
                h1b[(g*4+rr2)*776 + px]      = f2u(fgelu(D0[rr2]));
                h1b[(16+g*4+rr2)*776 + px]   = f2u(fgelu(D1[rr2]));
            }
        }
        __syncthreads();
        // ---- dw conv (+bias+gelu), row-contiguous ownership
        int chdw = cc*32 + cjdw;
        float w9[9];
        #pragma unroll
        for (int i=0;i<9;++i) w9[i] = dww[chdw*9+i];
        float bj = dwb[chdw];
        ushort8 uv[4];
        #pragma unroll
        for (int k=0;k<4;++k){
            float acc[8];
            #pragma unroll
            for (int i=0;i<8;++i) acc[i]=0.f;
            #pragma unroll
            for (int ky=0;ky<3;++ky){
                int gy = y0 + k + ky - 1;
                if (gy >= 0 && gy < HH){
                    const unsigned short* rp = h1b + cjdw*776 + (k+ky)*128 + pxg*8;
                    ushort8 mv = *(const ushort8*)rp;
                    float m[8];
                    #pragma unroll
                    for (int i=0;i<8;++i) m[i]=u2f(mv[i]);
                    float lf = (pxg>0)  ? u2f(rp[-1]) : 0.f;
                    float rt = (pxg<15) ? u2f(rp[8])  : 0.f;
                    float w0=w9[ky*3], w1=w9[ky*3+1], wv2=w9[ky*3+2];
                    #pragma unroll
                    for (int i=0;i<8;++i){
                        float l  = i ? m[i-1] : lf;
                        float rr_ = (i==7) ? rt : m[i+1];
                        acc[i] = fmaf(w0,l, fmaf(w1,m[i], fmaf(wv2,rr_,acc[i])));
                    }
                }
            }
            ushort8 o;
            #pragma unroll
            for (int i=0;i<8;++i) o[i] = f2u(fgelu(acc[i]+bj));
            uv[k]=o;
        }
        __syncthreads();
        #pragma unroll
        for (int k=0;k<4;++k)
            *(ushort8*)(h1b + cjdw*776 + (k+1)*128 + pxg*8) = uv[k];
        __syncthreads();
        // ---- lin2 phase fragments (phase-local)
        bf16x8 A1g[2][2], A2[2];
        #pragma unroll
        for (int t2=0;t2<2;++t2)
          #pragma unroll
          for (int kh=0;kh<2;++kh){
            bf16x8 fb;
            #pragma unroll
            for (int j=0;j<8;++j){
                int cin = kh*32 + g*8 + j;
                fb[j] = (short)f2u(l1w[cin*256 + 128 + cc*32 + t2*16 + col]);
            }
            A1g[t2][kh]=fb;
          }
        #pragma unroll
        for (int ot=0;ot<2;++ot){
            bf16x8 f;
            #pragma unroll
            for (int j=0;j<8;++j){
                int k = cc*32 + ((j>>2)<<4) + (g<<2) + (j&3);
                f[j] = (short)f2u(w2[k*64 + og*32 + ot*16 + col]);
            }
            A2[ot] = f;
        }
        // ---- lin2 accumulation with LAZY h2 (4 MFMA recompute h2 from xs,
        //      gelu, multiply by u from h1b, feed lin2 MFMAs)
        #pragma unroll
        for (int pt=0;pt<8;++pt){
            int px = (r+1)*128 + pt*16 + col;
            bf16x8 B0 = *(const bf16x8*)((char*)xs + px*128 + ((g*16) ^ ((px&7)<<4)));
            bf16x8 B1 = *(const bf16x8*)((char*)xs + px*128 + ((64 + g*16) ^ ((px&7)<<4)));
            f32x4 D0 = *(const f32x4*)(l1b + 128 + cc*32 + g*4);
            f32x4 D1 = *(const f32x4*)(l1b + 128 + cc*32 + 16 + g*4);
            D0 = __builtin_amdgcn_mfma_f32_16x16x32_bf16(A1g[0][0], B0, D0, 0,0,0);
            D0 = __builtin_amdgcn_mfma_f32_16x16x32_bf16(A1g[0][1], B1, D0, 0,0,0);
            D1 = __builtin_amdgcn_mfma_f32_16x16x32_bf16(A1g[1][0], B0, D1, 0,0,0);
            D1 = __builtin_amdgcn_mfma_f32_16x16x32_bf16(A1g[1][1], B1, D1, 0,0,0);
            bf16x8 Bg;
            #pragma unroll
            for (int j=0;j<4;++j){
                int cj0 = (g<<2) + j;
                int cj1 = 16 + (g<<2) + j;
                float u0 = u2f(h1b[cj0*776 + px]);
                float u1 = u2f(h1b[cj1*776 + px]);
                Bg[j]   = (short)f2u(u0 * fgelu(D0[j]));
                Bg[4+j] = (short)f2u(u1 * fgelu(D1[j]));
            }
            Dx[pt][0] = __builtin_amdgcn_mfma_f32_16x16x32_bf16(A2[0], Bg, Dx[pt][0], 0,0,0);
            Dx[pt][1] = __builtin_amdgcn_mfma_f32_16x16x32_bf16(A2[1], Bg, Dx[pt][1], 0,0,0);
        }
        __syncthreads();
    }
    // ---- epilogue: + residual v, write x (and x+x_init for last layer)
    const int y = y0 + r;
    #pragma unroll
    for (int pt=0;pt<8;++pt)
        #pragma unroll
        for (int ot=0;ot<2;++ot)
            #pragma unroll
            for (int rr2=0;rr2<4;++rr2){
                int ch = og*32 + ot*16 + g*4 + rr2;
                size_t off = ((size_t)b*CC + ch)*HWS + (size_t)y*WW + pt*16 + col;
                float rv = Dx[pt][ot][rr2] + b2f(v[off]);
                *reinterpret_cast<unsigned short*>(xout + off) = f2u(rv);
                if (xinit){
                    float s = rv + xinit[off];
                    *reinterpret_cast<unsigned short*>(xsum + off) = f2u(s);
                }
            }
}

// ---------------------------------------------------------------- final conv (64->1, 3x3), 4 px/thread
__global__ __launch_bounds__(256) void k_final(
    const bf16* __restrict__ s, const float* __restrict__ w,
    const float* __restrict__ bias, float* __restrict__ out)
{
    int gid = blockIdx.x*256 + threadIdx.x;
    int b = gid >> 12;
    int sp4 = (gid & 4095) << 2;
    int y = sp4 >> 7, x0 = sp4 & 127;
    const bf16* sb = s + (size_t)b*CC*HWS;
    float acc[4];
    #pragma unroll
    for (int i=0;i<4;++i) acc[i] = bias[0];

    #pragma unroll 1
    for (int c=0;c<CC;++c){
        const bf16* ip = sb + (size_t)c*HWS;
        const float* wp = w + (size_t)c*9;
        #pragma unroll
        for (int ky=0;ky<3;++ky){
            int yy = y + ky - 1;
            float xv[6];
            if (yy >= 0 && yy < HH){
                const bf16* rp = ip + yy*WW + x0;
                ushort4v mv = *reinterpret_cast<const ushort4v*>(rp);
                xv[1]=u2f(mv[0]); xv[2]=u2f(mv[1]); xv[3]=u2f(mv[2]); xv[4]=u2f(mv[3]);
                xv[0] = (x0>0)    ? b2f(rp[-1]) : 0.f;
                xv[5] = (x0+4<WW) ? b2f(rp[4])  : 0.f;
            } else {
                #pragma unroll
                for (int i=0;i<6;++i) xv[i] = 0.f;
            }
            float w0 = wp[ky*3+0], w1 = wp[ky*3+1], w2 = wp[ky*3+2];
            #pragma unroll
            for (int i=0;i<4;++i)
                acc[i] = fmaf(w0, xv[i],
                         fmaf(w1, xv[i+1],
                         fmaf(w2, xv[i+2], acc[i])));
        }
    }
    float4v ov; ov.x=acc[0]; ov.y=acc[1]; ov.z=acc[2]; ov.w=acc[3];
    *reinterpret_cast<float4v*>(out + (size_t)gid*4) = ov;
}

// ---------------------------------------------------------------- launch
extern "C" void kernel_launch(void* const* d_in, const int* in_sizes, int n_in,
                              void* d_out, int out_size, void* d_ws, size_t ws_size,
                              hipStream_t stream)
{
    const float* x    = (const float*)d_in[0];
    const float* wz1  = (const float*)d_in[1];
    const float* bz1  = (const float*)d_in[2];
    const float* wz2  = (const float*)d_in[3];
    const float* bz2  = (const float*)d_in[4];
    const float* wf1  = (const float*)d_in[5];
    const float* bf1  = (const float*)d_in[6];
    const float* wf2  = (const float*)d_in[7];
    const float* bf2  = (const float*)d_in[8];
    const float* pw   = (const float*)d_in[9];
    const float* l1w  = (const float*)d_in[10];
    const float* l1b  = (const float*)d_in[11];
    const float* dww  = (const float*)d_in[12];
    const float* dwb  = (const float*)d_in[13];
    const float* l2w  = (const float*)d_in[14];
    const float* l2b  = (const float*)d_in[15];
    const float* ow   = (const float*)d_in[16];
    const float* obb  = (const float*)d_in[17];

    char* ws = (char*)d_ws;
    bf16* xc    = (bf16*)(ws);                    // 33,554,432 B
    bf16* v     = (bf16*)(ws + 33554432);         // 33,554,432 B
    bf16* x1    = (bf16*)(ws + 67108864);         //  8,388,608 B
    bf16* xsumb = (bf16*)(ws + 75497472);         // 33,554,432 B

    k_convert<<<(NPIX*CC)/(256*8), 256, 0, stream>>>(x, xc, NPIX*CC);
    for (int l=0;l<3;++l){
        k_gate <<<512, 256, 0, stream>>>(xc,
                wz1 + l*CC*CC, bz1 + l*CC, wz2 + l*CC*CC, bz2 + l*CC,
                wf1 + l*CC*CC, bf1 + l*CC, wf2 + l*CC*CC, bf2 + l*CC, v);
        k_pconv<<<NPIX/(256*4), 256, 0, stream>>>(v, pw + l*DCC*DCC*9, x1);
        k_mid  <<<512, 512, 0, stream>>>(x1, v,
                l1w + l*CC*256, l1b + l*256,
                dww + l*HIDN*9, dwb + l*HIDN,
                l2w + l*HIDN*CC, l2b + l*CC,
                xc, (l==2) ? x : nullptr, xsumb);
    }
    k_final<<<NPIX/(256*4), 256, 0, stream>>>(xsumb, ow, obb, (float*)d_out);
}

// Round 8
// 912.218 us; speedup vs baseline: 1.6391x; 1.6391x over previous
//
#include <hip/hip_runtime.h>
#include <hip/hip_bf16.h>

#define CC 64
#define HIDN 128
#define DCC 16
#define HH 128
#define WW 128
#define HWS (HH*WW)        // 16384
#define BB 16
#define NPIX (BB*HWS)      // 262144

typedef __hip_bfloat16 bf16;
typedef __attribute__((ext_vector_type(8))) unsigned short ushort8;
typedef __attribute__((ext_vector_type(4))) unsigned short ushort4v;
typedef __attribute__((ext_vector_type(4))) float float4v;
typedef __attribute__((ext_vector_type(8))) short bf16x8;
typedef __attribute__((ext_vector_type(4))) float f32x4;

__device__ __forceinline__ float rcp_fast(float x){ return __builtin_amdgcn_rcpf(x); }
__device__ __forceinline__ float ftanh(float x){
    float e = __expf(2.f*x);
    return 1.f - 2.f*rcp_fast(e + 1.f);
}
__device__ __forceinline__ float fsig(float x){
    return rcp_fast(1.f + __expf(-x));
}
__device__ __forceinline__ float fgelu(float x){
    return x * fsig(x*(1.5957691216f + 0.07135481283f*x*x));
}
__device__ __forceinline__ float b2f(bf16 v){ return __bfloat162float(v); }
__device__ __forceinline__ bf16  f2b(float v){ return __float2bfloat16(v); }
__device__ __forceinline__ float u2f(unsigned short u){
    unsigned v = ((unsigned)u) << 16; return __uint_as_float(v);
}
__device__ __forceinline__ unsigned short f2u(float f){
    bf16 h = __float2bfloat16(f);
    return *reinterpret_cast<unsigned short*>(&h);
}
__device__ __forceinline__ bf16x8 packf(float4v a, float4v b){
    bf16x8 r;
    r[0]=(short)f2u(a.x); r[1]=(short)f2u(a.y); r[2]=(short)f2u(a.z); r[3]=(short)f2u(a.w);
    r[4]=(short)f2u(b.x); r[5]=(short)f2u(b.y); r[6]=(short)f2u(b.z); r[7]=(short)f2u(b.w);
    return r;
}

// ---------------------------------------------------------------- convert
__global__ __launch_bounds__(256) void k_convert(const float* __restrict__ in,
                                                 bf16* __restrict__ out, int n){
    int i = (blockIdx.x*256 + threadIdx.x) * 8;
    if (i >= n) return;
    const float4v* ip = reinterpret_cast<const float4v*>(in + i);
    float4v a = ip[0], b = ip[1];
    ushort8 o;
    o[0]=f2u(a.x); o[1]=f2u(a.y); o[2]=f2u(a.z); o[3]=f2u(a.w);
    o[4]=f2u(b.x); o[5]=f2u(b.y); o[6]=f2u(b.z); o[7]=f2u(b.w);
    *reinterpret_cast<ushort8*>(out + i) = o;
}

// ---------------------------------------------------------------- gate (MFMA, zero-shuffle chain)
__global__ __launch_bounds__(256,2) void k_gate(
    const bf16* __restrict__ xin,
    const float* __restrict__ wz1, const float* __restrict__ bz1,
    const float* __restrict__ wz2, const float* __restrict__ bz2,
    const float* __restrict__ wf1, const float* __restrict__ bf1,
    const float* __restrict__ wf2, const float* __restrict__ bf2,
    bf16* __restrict__ vout)
{
    const int t = threadIdx.x;
    const int lane = t & 63;
    const int wv = t >> 6;
    const int col = lane & 15;
    const int g = lane >> 4;
    const int blk = blockIdx.x;
    const int b = blk >> 5;
    const int sp0 = (blk & 31) << 9;

    bf16x8 Az1[4][2], Af1[4][2], Az2[4][2], Af2[4][2];
    #pragma unroll
    for (int ot=0; ot<4; ++ot){
        #pragma unroll
        for (int kh=0; kh<2; ++kh){
            const float* p;
            p = wz1 + (ot*16+col)*64 + kh*32 + g*8;
            Az1[ot][kh] = packf(*(const float4v*)p, *(const float4v*)(p+4));
            p = wf1 + (ot*16+col)*64 + kh*32 + g*8;
            Af1[ot][kh] = packf(*(const float4v*)p, *(const float4v*)(p+4));
            p = wz2 + (ot*16+col)*64 + kh*32 + g*4;
            Az2[ot][kh] = packf(*(const float4v*)p, *(const float4v*)(p+16));
            p = wf2 + (ot*16+col)*64 + kh*32 + g*4;
            Af2[ot][kh] = packf(*(const float4v*)p, *(const float4v*)(p+16));
        }
    }
    const bf16* xb = xin + (size_t)b*CC*HWS;
    bf16*       vb = vout + (size_t)b*CC*HWS;

    for (int it = wv; it < 32; it += 4){
        const int px = sp0 + it*16 + col;
        bf16x8 Bx[2];
        #pragma unroll
        for (int kh=0; kh<2; ++kh)
            #pragma unroll
            for (int j=0; j<8; ++j){
                int c = kh*32 + g*8 + j;
                Bx[kh][j] = *reinterpret_cast<const short*>(xb + (size_t)c*HWS + px);
            }
        f32x4 Dz[4], Df[4];
        #pragma unroll
        for (int ot=0; ot<4; ++ot){
            Dz[ot] = *(const f32x4*)(bz1 + ot*16 + g*4);
            Df[ot] = *(const f32x4*)(bf1 + ot*16 + g*4);
        }
        #pragma unroll
        for (int kh=0; kh<2; ++kh)
            #pragma unroll
            for (int ot=0; ot<4; ++ot){
                Dz[ot] = __builtin_amdgcn_mfma_f32_16x16x32_bf16(Az1[ot][kh], Bx[kh], Dz[ot], 0,0,0);
                Df[ot] = __builtin_amdgcn_mfma_f32_16x16x32_bf16(Af1[ot][kh], Bx[kh], Df[ot], 0,0,0);
            }
        #pragma unroll
        for (int ot=0; ot<4; ++ot)
            #pragma unroll
            for (int r=0; r<4; ++r){
                Dz[ot][r] = ftanh(Dz[ot][r]);
                Df[ot][r] = ftanh(Df[ot][r]);
            }
        bf16x8 Bz[2], Bf[2];
        #pragma unroll
        for (int kh=0; kh<2; ++kh)
            #pragma unroll
            for (int j=0; j<4; ++j){
                Bz[kh][j]   = (short)f2u(Dz[2*kh][j]);
                Bz[kh][4+j] = (short)f2u(Dz[2*kh+1][j]);
                Bf[kh][j]   = (short)f2u(Df[2*kh][j]);
                Bf[kh][4+j] = (short)f2u(Df[2*kh+1][j]);
            }
        f32x4 Ez[4], Ef[4];
        #pragma unroll
        for (int ot=0; ot<4; ++ot){
            Ez[ot] = *(const f32x4*)(bz2 + ot*16 + g*4);
            Ef[ot] = *(const f32x4*)(bf2 + ot*16 + g*4);
        }
        #pragma unroll
        for (int kh=0; kh<2; ++kh)
            #pragma unroll
            for (int ot=0; ot<4; ++ot){
                Ez[ot] = __builtin_amdgcn_mfma_f32_16x16x32_bf16(Az2[ot][kh], Bz[kh], Ez[ot], 0,0,0);
                Ef[ot] = __builtin_amdgcn_mfma_f32_16x16x32_bf16(Af2[ot][kh], Bf[kh], Ef[ot], 0,0,0);
            }
        #pragma unroll
        for (int ot=0; ot<4; ++ot)
            #pragma unroll
            for (int r=0; r<4; ++r){
                float Zv = ftanh(Ez[ot][r]);
                float Fv = fsig(Ef[ot][r]);
                *reinterpret_cast<unsigned short*>(vb + (size_t)(ot*16+g*4+r)*HWS + px)
                    = f2u((1.f - Fv)*Zv);
            }
    }
}

// ---------------------------------------------------------------- pconv (16->16, 3x3), 4 px/thread
__global__ __launch_bounds__(256) void k_pconv(
    const bf16* __restrict__ v, const float* __restrict__ w, bf16* __restrict__ x1)
{
    int gid = blockIdx.x*256 + threadIdx.x;
    int b = gid >> 12;
    int sp4 = (gid & 4095) << 2;
    int y = sp4 >> 7, x0 = sp4 & 127;
    const bf16* vb = v + (size_t)b*CC*HWS;
    float acc[DCC][4];
    #pragma unroll
    for (int o=0;o<DCC;++o)
        #pragma unroll
        for (int i=0;i<4;++i) acc[o][i] = 0.f;

    #pragma unroll 1
    for (int ic=0; ic<DCC; ++ic){
        const bf16* ip = vb + (size_t)ic*HWS;
        float xv[3][6];
        #pragma unroll
        for (int ky=0;ky<3;++ky){
            int yy = y + ky - 1;
            if (yy >= 0 && yy < HH){
                const bf16* rp = ip + yy*WW + x0;
                ushort4v mv = *reinterpret_cast<const ushort4v*>(rp);
                xv[ky][1]=u2f(mv[0]); xv[ky][2]=u2f(mv[1]);
                xv[ky][3]=u2f(mv[2]); xv[ky][4]=u2f(mv[3]);
                xv[ky][0] = (x0>0)     ? b2f(rp[-1]) : 0.f;
                xv[ky][5] = (x0+4<WW)  ? b2f(rp[4])  : 0.f;
            } else {
                #pragma unroll
                for (int i=0;i<6;++i) xv[ky][i] = 0.f;
            }
        }
        #pragma unroll
        for (int o=0;o<DCC;++o){
            const float* wp = w + (size_t)(o*DCC+ic)*9;
            #pragma unroll
            for (int ky=0;ky<3;++ky){
                float w0 = wp[ky*3+0], w1 = wp[ky*3+1], w2 = wp[ky*3+2];
                #pragma unroll
                for (int i=0;i<4;++i)
                    acc[o][i] = fmaf(w0, xv[ky][i],
                                fmaf(w1, xv[ky][i+1],
                                fmaf(w2, xv[ky][i+2], acc[o][i])));
            }
        }
    }
    bf16* xo = x1 + (size_t)b*DCC*HWS + sp4;
    #pragma unroll
    for (int o=0;o<DCC;++o){
        ushort4v ov;
        #pragma unroll
        for (int i=0;i<4;++i) ov[i] = f2u(acc[o][i]);
        *reinterpret_cast<ushort4v*>(xo + (size_t)o*HWS) = ov;
    }
}

// ---------------------------------------------------------------- midA: lin1(h1)+gelu+dwconv+gelu + lazy-h2+gelu + gate -> g
// Block: 512 thr (8 waves), 4 output rows x 128 px. No persistent accumulators
// across phases (R4-R7 post-mortem: 64-VGPR lin2 accumulator held across phases
// forced ~700 MB/dispatch scratch spills at the 128-VGPR allocation).
__global__ __launch_bounds__(512) void k_midA(
    const bf16* __restrict__ x1, const bf16* __restrict__ v,
    const float* __restrict__ l1w, const float* __restrict__ l1b,
    const float* __restrict__ dww, const float* __restrict__ dwb,
    bf16* __restrict__ gout)
{
    __shared__ __align__(16) unsigned short xs[768*64];    // [px][ch] swizzled, 98304 B
    __shared__ __align__(16) unsigned short h1b[32*778];   // [cj][778], 49792 B
    const int t = threadIdx.x;
    const int lane = t & 63;
    const int w = t >> 6;
    const int col = lane & 15;
    const int g = lane >> 4;
    const int blk = blockIdx.x;
    const int b = blk >> 5;
    const int y0 = (blk & 31) << 2;

    // ---- stage x-cat: 64 ch x 6 rows(y0-1..y0+4) x 128 px, transposed+swizzled
    {
        const int ch = t & 63;
        const int wg = t >> 6;
        const bf16* src = (ch < DCC) ? x1 + ((size_t)b*DCC + ch)*HWS
                                     : v  + ((size_t)b*CC  + ch)*HWS;
        #pragma unroll
        for (int i=0;i<12;++i){
            int pxg = wg*12 + i;          // 0..95
            int bufpx = pxg << 3;
            int rr = bufpx >> 7;
            int xcol = bufpx & 127;
            int gy = y0 - 1 + rr;
            ushort8 val;
            #pragma unroll
            for (int j=0;j<8;++j) val[j] = 0;
            if (gy >= 0 && gy < HH)
                val = *reinterpret_cast<const ushort8*>(src + (size_t)gy*WW + xcol);
            #pragma unroll
            for (int j=0;j<8;++j){
                int px = bufpx + j;
                *(unsigned short*)((char*)xs + px*128 + ((ch*2) ^ ((px&7)<<4))) = val[j];
            }
        }
    }
    __syncthreads();

    const int cjdw = t & 31;          // dw: channel within chunk
    const int pxg  = (t>>5) & 15;     // dw: 8-px group

    #pragma unroll 1
    for (int cc=0; cc<4; ++cc){
        // ---- pass A fragments (h1 weights)
        bf16x8 A1h[2][2];
        #pragma unroll
        for (int t2=0;t2<2;++t2)
          #pragma unroll
          for (int kh=0;kh<2;++kh){
            bf16x8 fa;
            #pragma unroll
            for (int j=0;j<8;++j){
                int cin = kh*32 + g*8 + j;
                fa[j] = (short)f2u(l1w[cin*256 + cc*32 + t2*16 + col]);
            }
            A1h[t2][kh]=fa;
          }
        // ---- pass A: h1 chunk (32 ch) on 6 rows -> h1b
        #pragma unroll
        for (int q=0;q<6;++q){
            int idx = w*6 + q;
            int rr = idx >> 3, pt = idx & 7;
            int px = rr*128 + pt*16 + col;
            bf16x8 B0 = *(const bf16x8*)((char*)xs + px*128 + ((g*16) ^ ((px&7)<<4)));
            bf16x8 B1 = *(const bf16x8*)((char*)xs + px*128 + ((64 + g*16) ^ ((px&7)<<4)));
            f32x4 D0 = *(const f32x4*)(l1b + cc*32 + g*4);
            f32x4 D1 = *(const f32x4*)(l1b + cc*32 + 16 + g*4);
            D0 = __builtin_amdgcn_mfma_f32_16x16x32_bf16(A1h[0][0], B0, D0, 0,0,0);
            D0 = __builtin_amdgcn_mfma_f32_16x16x32_bf16(A1h[0][1], B1, D0, 0,0,0);
            D1 = __builtin_amdgcn_mfma_f32_16x16x32_bf16(A1h[1][0], B0, D1, 0,0,0);
            D1 = __builtin_amdgcn_mfma_f32_16x16x32_bf16(A1h[1][1], B1, D1, 0,0,0);
            #pragma unroll
            for (int rr2=0;rr2<4;++rr2){
                h1b[(g*4+rr2)*778 + px]      = f2u(fgelu(D0[rr2]));
                h1b[(16+g*4+rr2)*778 + px]   = f2u(fgelu(D1[rr2]));
            }
        }
        __syncthreads();
        // ---- dw conv (+bias+gelu) -> uv regs
        int chdw = cc*32 + cjdw;
        float w9[9];
        #pragma unroll
        for (int i=0;i<9;++i) w9[i] = dww[chdw*9+i];
        float bj = dwb[chdw];
        ushort8 uv[4];
        #pragma unroll
        for (int k=0;k<4;++k){
            float acc[8];
            #pragma unroll
            for (int i=0;i<8;++i) acc[i]=0.f;
            #pragma unroll
            for (int ky=0;ky<3;++ky){
                int gy = y0 + k + ky - 1;
                if (gy >= 0 && gy < HH){
                    const unsigned short* rp = h1b + cjdw*778 + (k+ky)*128 + pxg*8;
                    ushort8 mv = *(const ushort8*)rp;
                    float m[8];
                    #pragma unroll
                    for (int i=0;i<8;++i) m[i]=u2f(mv[i]);
                    float lf = (pxg>0)  ? u2f(rp[-1]) : 0.f;
                    float rt = (pxg<15) ? u2f(rp[8])  : 0.f;
                    float w0=w9[ky*3], w1=w9[ky*3+1], wv2=w9[ky*3+2];
                    #pragma unroll
                    for (int i=0;i<8;++i){
                        float l  = i ? m[i-1] : lf;
                        float rr_ = (i==7) ? rt : m[i+1];
                        acc[i] = fmaf(w0,l, fmaf(w1,m[i], fmaf(wv2,rr_,acc[i])));
                    }
                }
            }
            ushort8 o;
            #pragma unroll
            for (int i=0;i<8;++i) o[i] = f2u(fgelu(acc[i]+bj));
            uv[k]=o;
        }
        __syncthreads();
        #pragma unroll
        for (int k=0;k<4;++k)
            *(ushort8*)(h1b + cjdw*778 + (k+1)*128 + pxg*8) = uv[k];
        __syncthreads();
        // ---- lazy h2 (4 MFMA per tile) + gate, write g directly to global
        bf16x8 A1g[2][2];
        #pragma unroll
        for (int t2=0;t2<2;++t2)
          #pragma unroll
          for (int kh=0;kh<2;++kh){
            bf16x8 fb;
            #pragma unroll
            for (int j=0;j<8;++j){
                int cin = kh*32 + g*8 + j;
                fb[j] = (short)f2u(l1w[cin*256 + 128 + cc*32 + t2*16 + col]);
            }
            A1g[t2][kh]=fb;
          }
        #pragma unroll
        for (int q=0;q<4;++q){
            int idx = w*4 + q;            // 0..31 = 4 rows x 8 pt
            int row = idx >> 3, pt = idx & 7;
            int px = (row+1)*128 + pt*16 + col;
            bf16x8 B0 = *(const bf16x8*)((char*)xs + px*128 + ((g*16) ^ ((px&7)<<4)));
            bf16x8 B1 = *(const bf16x8*)((char*)xs + px*128 + ((64 + g*16) ^ ((px&7)<<4)));
            f32x4 D0 = *(const f32x4*)(l1b + 128 + cc*32 + g*4);
            f32x4 D1 = *(const f32x4*)(l1b + 128 + cc*32 + 16 + g*4);
            D0 = __builtin_amdgcn_mfma_f32_16x16x32_bf16(A1g[0][0], B0, D0, 0,0,0);
            D0 = __builtin_amdgcn_mfma_f32_16x16x32_bf16(A1g[0][1], B1, D0, 0,0,0);
            D1 = __builtin_amdgcn_mfma_f32_16x16x32_bf16(A1g[1][0], B0, D1, 0,0,0);
            D1 = __builtin_amdgcn_mfma_f32_16x16x32_bf16(A1g[1][1], B1, D1, 0,0,0);
            size_t pix = (size_t)(y0+row)*WW + pt*16 + col;
            #pragma unroll
            for (int rr2=0;rr2<4;++rr2){
                int cj0 = g*4 + rr2, cj1 = 16 + g*4 + rr2;
                float u0 = u2f(h1b[cj0*778 + px]);
                float u1 = u2f(h1b[cj1*778 + px]);
                *reinterpret_cast<unsigned short*>(gout + ((size_t)(b*HIDN + cc*32 + cj0))*HWS + pix)
                    = f2u(u0 * fgelu(D0[rr2]));
                *reinterpret_cast<unsigned short*>(gout + ((size_t)(b*HIDN + cc*32 + cj1))*HWS + pix)
                    = f2u(u1 * fgelu(D1[rr2]));
            }
        }
        __syncthreads();
    }
}

// ---------------------------------------------------------------- midB: lin2 (128->64) + bias + residual
// Block: 512 px, 512 thr. g staged coalesced into LDS (stride 514: bank-spread).
__global__ __launch_bounds__(512) void k_midB(
    const bf16* __restrict__ gin,
    const float* __restrict__ w2, const float* __restrict__ l2b,
    const bf16* __restrict__ v,
    bf16* __restrict__ xout,
    const float* __restrict__ xinit,   // non-null on last layer
    bf16* __restrict__ xsum)
{
    __shared__ __align__(16) unsigned short gs[HIDN*514];  // 131584 B
    const int t = threadIdx.x;
    const int lane = t & 63;
    const int w = t >> 6;
    const int col = lane & 15;
    const int g = lane >> 4;
    const int blk = blockIdx.x;
    const int b = blk >> 5;
    const int sp0 = (blk & 31) << 9;

    // ---- stage g: 128 ch x 512 px, coalesced
    {
        const int ch = t >> 2;
        const int part = t & 3;
        const bf16* gb = gin + ((size_t)(b*HIDN + ch))*HWS + sp0 + part*128;
        #pragma unroll
        for (int i=0;i<16;++i){
            ushort8 u8 = *reinterpret_cast<const ushort8*>(gb + i*8);
            *reinterpret_cast<ushort8*>(gs + ch*514 + part*128 + i*8) = u8;
        }
    }
    __syncthreads();

    // ---- A fragments: A[ot][kh] slot (g,j) = w2[kh*32+g*8+j][ot*16+col]
    bf16x8 A[4][4];
    #pragma unroll
    for (int ot=0;ot<4;++ot)
        #pragma unroll
        for (int kh=0;kh<4;++kh){
            bf16x8 f;
            #pragma unroll
            for (int j=0;j<8;++j){
                int k = kh*32 + g*8 + j;
                f[j] = (short)f2u(w2[k*64 + ot*16 + col]);
            }
            A[ot][kh] = f;
        }

    #pragma unroll 1
    for (int q=0;q<4;++q){
        int ptg = w*4 + q;               // 0..31
        int px = ptg*16 + col;
        bf16x8 Bg[4];
        #pragma unroll
        for (int kh=0;kh<4;++kh)
            #pragma unroll
            for (int j=0;j<8;++j)
                Bg[kh][j] = (short)gs[(kh*32 + g*8 + j)*514 + px];
        f32x4 D[4];
        #pragma unroll
        for (int ot=0;ot<4;++ot)
            D[ot] = *(const f32x4*)(l2b + ot*16 + g*4);
        #pragma unroll
        for (int kh=0;kh<4;++kh)
            #pragma unroll
            for (int ot=0;ot<4;++ot)
                D[ot] = __builtin_amdgcn_mfma_f32_16x16x32_bf16(A[ot][kh], Bg[kh], D[ot], 0,0,0);
        #pragma unroll
        for (int ot=0;ot<4;++ot)
            #pragma unroll
            for (int rr2=0;rr2<4;++rr2){
                int ch = ot*16 + g*4 + rr2;
                size_t off = ((size_t)(b*CC + ch))*HWS + sp0 + px;
                float rv = D[ot][rr2] + b2f(v[off]);
                *reinterpret_cast<unsigned short*>(xout + off) = f2u(rv);
                if (xinit){
                    float s = rv + xinit[off];
                    *reinterpret_cast<unsigned short*>(xsum + off) = f2u(s);
                }
            }
    }
}

// ---------------------------------------------------------------- final conv (64->1, 3x3), 4 px/thread
__global__ __launch_bounds__(256) void k_final(
    const bf16* __restrict__ s, const float* __restrict__ w,
    const float* __restrict__ bias, float* __restrict__ out)
{
    int gid = blockIdx.x*256 + threadIdx.x;
    int b = gid >> 12;
    int sp4 = (gid & 4095) << 2;
    int y = sp4 >> 7, x0 = sp4 & 127;
    const bf16* sb = s + (size_t)b*CC*HWS;
    float acc[4];
    #pragma unroll
    for (int i=0;i<4;++i) acc[i] = bias[0];

    #pragma unroll 1
    for (int c=0;c<CC;++c){
        const bf16* ip = sb + (size_t)c*HWS;
        const float* wp = w + (size_t)c*9;
        #pragma unroll
        for (int ky=0;ky<3;++ky){
            int yy = y + ky - 1;
            float xv[6];
            if (yy >= 0 && yy < HH){
                const bf16* rp = ip + yy*WW + x0;
                ushort4v mv = *reinterpret_cast<const ushort4v*>(rp);
                xv[1]=u2f(mv[0]); xv[2]=u2f(mv[1]); xv[3]=u2f(mv[2]); xv[4]=u2f(mv[3]);
                xv[0] = (x0>0)    ? b2f(rp[-1]) : 0.f;
                xv[5] = (x0+4<WW) ? b2f(rp[4])  : 0.f;
            } else {
                #pragma unroll
                for (int i=0;i<6;++i) xv[i] = 0.f;
            }
            float w0 = wp[ky*3+0], w1 = wp[ky*3+1], w2 = wp[ky*3+2];
            #pragma unroll
            for (int i=0;i<4;++i)
                acc[i] = fmaf(w0, xv[i],
                         fmaf(w1, xv[i+1],
                         fmaf(w2, xv[i+2], acc[i])));
        }
    }
    float4v ov; ov.x=acc[0]; ov.y=acc[1]; ov.z=acc[2]; ov.w=acc[3];
    *reinterpret_cast<float4v*>(out + (size_t)gid*4) = ov;
}

// ---------------------------------------------------------------- launch
extern "C" void kernel_launch(void* const* d_in, const int* in_sizes, int n_in,
                              void* d_out, int out_size, void* d_ws, size_t ws_size,
                              hipStream_t stream)
{
    const float* x    = (const float*)d_in[0];
    const float* wz1  = (const float*)d_in[1];
    const float* bz1  = (const float*)d_in[2];
    const float* wz2  = (const float*)d_in[3];
    const float* bz2  = (const float*)d_in[4];
    const float* wf1  = (const float*)d_in[5];
    const float* bf1  = (const float*)d_in[6];
    const float* wf2  = (const float*)d_in[7];
    const float* bf2  = (const float*)d_in[8];
    const float* pw   = (const float*)d_in[9];
    const float* l1w  = (const float*)d_in[10];
    const float* l1b  = (const float*)d_in[11];
    const float* dww  = (const float*)d_in[12];
    const float* dwb  = (const float*)d_in[13];
    const float* l2w  = (const float*)d_in[14];
    const float* l2b  = (const float*)d_in[15];
    const float* ow   = (const float*)d_in[16];
    const float* obb  = (const float*)d_in[17];

    char* ws = (char*)d_ws;
    bf16* xc    = (bf16*)(ws);                    // 33,554,432 B
    bf16* v     = (bf16*)(ws + 33554432);         // 33,554,432 B
    bf16* x1    = (bf16*)(ws + 67108864);         //  8,388,608 B
    bf16* xsumb = (bf16*)(ws + 75497472);         // 33,554,432 B
    bf16* gbuf  = (bf16*)(ws + 109051904);        // 67,108,864 B (total ~176 MB)

    k_convert<<<(NPIX*CC)/(256*8), 256, 0, stream>>>(x, xc, NPIX*CC);
    for (int l=0;l<3;++l){
        k_gate <<<512, 256, 0, stream>>>(xc,
                wz1 + l*CC*CC, bz1 + l*CC, wz2 + l*CC*CC, bz2 + l*CC,
                wf1 + l*CC*CC, bf1 + l*CC, wf2 + l*CC*CC, bf2 + l*CC, v);
        k_pconv<<<NPIX/(256*4), 256, 0, stream>>>(v, pw + l*DCC*DCC*9, x1);
        k_midA <<<512, 512, 0, stream>>>(x1, v,
                l1w + l*CC*256, l1b + l*256,
                dww + l*HIDN*9, dwb + l*HIDN, gbuf);
        k_midB <<<512, 512, 0, stream>>>(gbuf,
                l2w + l*HIDN*CC, l2b + l*CC, v, xc,
                (l==2) ? x : nullptr, xsumb);
    }
    k_final<<<NPIX/(256*4), 256, 0, stream>>>(xsumb, ow, obb, (float*)d_out);
}